// Round 20
// baseline (147.520 us; speedup 1.0000x reference)
//
#include <hip/hip_runtime.h>
#include <stdint.h>

#define B_   4
#define S_   2048
#define E_   1024
#define MQKV (B_ * S_)
#define LDP  2112   // padded row stride (u16) for Pm and vt

typedef __bf16 bf16x8 __attribute__((ext_vector_type(8)));
typedef float f32x4 __attribute__((ext_vector_type(4)));
typedef unsigned short u16;
typedef unsigned int u32;

__device__ __forceinline__ u16 f2bf(float x) {
  union { float f; u32 u; } c; c.f = x;
  u32 r = (c.u + 0x7FFFu + ((c.u >> 16) & 1u)) >> 16;
  return (u16)r;
}
__device__ __forceinline__ float bf2f(u16 h) {
  union { u32 u; float f; } c; c.u = ((u32)h) << 16;
  return c.f;
}

// convert x, Wq, Wk, Wv to bf16 (dst = xb|wqkv contiguous)
__global__ __launch_bounds__(256) void cvt_all(
    const float* __restrict__ x, const float* __restrict__ wq,
    const float* __restrict__ wk, const float* __restrict__ wv,
    u16* __restrict__ dst) {
  const int gid = blockIdx.x * 256 + threadIdx.x;
  const int total = 2097152 + 786432;
  const int stride = gridDim.x * 256;
  for (int i = gid; i < total; i += stride) {
    float4 f;
    if (i < 2097152) {
      f = reinterpret_cast<const float4*>(x)[i];
    } else {
      const int j = i - 2097152;
      const int sel = j >> 18;
      const int r = j & 262143;
      const float* s = sel == 0 ? wq : (sel == 1 ? wk : wv);
      f = reinterpret_cast<const float4*>(s)[r];
    }
    ushort4 o;
    o.x = f2bf(f.x); o.y = f2bf(f.y); o.z = f2bf(f.z); o.w = f2bf(f.w);
    reinterpret_cast<ushort4*>(dst)[i] = o;
  }
}

#define GLOAD_LDS16(g, l)                                                      \
  __builtin_amdgcn_global_load_lds(                                            \
      (const __attribute__((address_space(1))) u32*)(g),                       \
      (__attribute__((address_space(3))) u32*)(l), 16, 0, 0)

// ============================================================================
// R10/R17/R18/R19-verified BK=32 ring GEMM body: BM=256, 8 waves (2Mx4N),
// 4-slot ring, counted vmcnt, 2-way-free XOR swizzle, setprio, XCD swizzle.
// EPI 0: qk-projection: +bias, scatter col<1024 -> q else -> k (ld 1024)
// EPI 1: v-projection-T: +b0[row], bf16, ldC-strided, z-batched
// EPI 2: exp(v*scale), bf16, ldC-strided + per-(row,block,wave) fp32 partial
//        sums via shfl (NO atomics) -> part = (float*)b0, [z][row][32]
// EPI 3: v * invL (invL computed in-epilogue from part = b0), fp32 nt-store
// ============================================================================
template <int BN, int EPI>
__device__ __forceinline__ void gemm_body(
    u16* __restrict__ ldsb, int id, int nwg,
    const u16* __restrict__ A, const u16* __restrict__ Bt, void* __restrict__ Cv,
    const float* __restrict__ b0, const float* __restrict__ b1,
    int N, int K, float scale,
    long sA, long sB, long sC, long ldA, long ldB, long ldC, int gx, int gy) {
  constexpr int BM = 256;
  constexpr int NR = BN / 64;
  constexpr int L  = 2 + BN / 128;
  constexpr int BSLOT = BN * 32;

  u16* lA = ldsb;
  u16* lB = ldsb + 4 * BM * 32;

  const int t = threadIdx.x;
  const int wv = t >> 6;
  const int ln = t & 63;
  const int wm = wv >> 2;
  const int wn = wv & 3;

  id = (id & 7) * (nwg >> 3) + (id >> 3);
  const int pz = gx * gy;
  const int z = id / pz;
  const int r2 = id - z * pz;
  const int by = r2 / gx;
  const int bx = r2 - by * gx;
  const int bm = by * BM;
  const int bn = bx * BN;

  A += (size_t)z * sA;
  Bt += (size_t)z * sB;

  const int srow = t >> 2;
  const int g0 = (t & 3) ^ ((srow >> 1) & 3);
  const u16* gA0 = A + (size_t)(bm + srow) * ldA + g0 * 8;
  const u16* gA1 = gA0 + (size_t)128 * ldA;
  const u16* gB0 = Bt + (size_t)(bn + srow) * ldB + g0 * 8;
  const u16* gB1 = gB0 + (size_t)128 * ldB;

  auto STAGE = [&](int u) {
    const int s = u & 3;
    const int ko = u * 32;
    GLOAD_LDS16(gA0 + ko, lA + s * 8192 + wv * 512);
    GLOAD_LDS16(gA1 + ko, lA + s * 8192 + 4096 + wv * 512);
    GLOAD_LDS16(gB0 + ko, lB + s * BSLOT + wv * 512);
    if constexpr (BN == 256) GLOAD_LDS16(gB1 + ko, lB + s * BSLOT + 4096 + wv * 512);
  };

  const int lrow = ln & 15;
  const int g = ln >> 4;
  const int aR = wm * 128 + lrow;
  const int aOff = aR * 32 + (g ^ ((aR >> 1) & 3)) * 8;
  const int bR = wn * (BN / 4) + lrow;
  const int bOff = bR * 32 + (g ^ ((bR >> 1) & 3)) * 8;

  f32x4 acc[8][NR] = {};
  const int T = K >> 5;

  bf16x8 afA[8], afB[8], bgA[NR], bgB[NR];

#define RD_A(DST, TILE) do { const u16* _p = lA + ((TILE) & 3) * 8192 + aOff;  \
  _Pragma("unroll") for (int _i = 0; _i < 8; ++_i)                             \
    DST[_i] = *reinterpret_cast<const bf16x8*>(_p + _i * 512); } while (0)
#define RD_B(DST, TILE) do { const u16* _p = lB + ((TILE) & 3) * BSLOT + bOff; \
  _Pragma("unroll") for (int _j = 0; _j < NR; ++_j)                            \
    DST[_j] = *reinterpret_cast<const bf16x8*>(_p + _j * 512); } while (0)
#define DO_MFMA(AF, BG) do { __builtin_amdgcn_s_setprio(1);                    \
  _Pragma("unroll") for (int _i = 0; _i < 8; ++_i)                             \
  _Pragma("unroll") for (int _j = 0; _j < NR; ++_j)                            \
    acc[_i][_j] = __builtin_amdgcn_mfma_f32_16x16x32_bf16(AF[_i], BG[_j],      \
                                                          acc[_i][_j], 0, 0, 0);\
  __builtin_amdgcn_s_setprio(0); } while (0)
#define VM_GATE(COND) do {                                                     \
  if (COND) { asm volatile("s_waitcnt vmcnt(%0)" :: "n"(L) : "memory"); }      \
  else { asm volatile("s_waitcnt vmcnt(0)" ::: "memory"); }                    \
  __builtin_amdgcn_s_barrier(); asm volatile("" ::: "memory"); } while (0)

  STAGE(0); STAGE(1); STAGE(2);
  asm volatile("s_waitcnt vmcnt(%0)" :: "n"(L) : "memory");
  __builtin_amdgcn_s_barrier();
  asm volatile("" ::: "memory");

  if constexpr (NR == 2) { RD_A(afA, 0); RD_B(bgA, 0); }
  else                   { RD_B(bgA, 0); }

  for (int tt = 0; tt < T; tt += 2) {
    if (tt + 3 < T) STAGE(tt + 3);
    if constexpr (NR == 2) { RD_A(afB, tt + 1); RD_B(bgB, tt + 1); DO_MFMA(afA, bgA); }
    else                   { RD_A(afA, tt); RD_B(bgB, tt + 1);     DO_MFMA(afA, bgA); }
    VM_GATE(tt + 3 < T);

    if (tt + 4 < T) STAGE(tt + 4);
    if constexpr (NR == 2) {
      if (tt + 2 < T) { RD_A(afA, tt + 2); RD_B(bgA, tt + 2); }
      DO_MFMA(afB, bgB);
    } else {
      RD_A(afA, tt + 1);
      if (tt + 2 < T) RD_B(bgA, tt + 2);
      DO_MFMA(afA, bgB);
    }
    VM_GATE(tt + 4 < T);
  }
#undef RD_A
#undef RD_B
#undef DO_MFMA
#undef VM_GATE

  const int r0 = (ln >> 4) * 4;
  const int c0 = ln & 15;
  if constexpr (EPI == 2) {
    // exp + store + per-row partial (shfl within 16-lane col group, 1 store)
    float* part = const_cast<float*>(b0);
#pragma unroll
    for (int i = 0; i < 8; ++i) {
#pragma unroll
      for (int ii = 0; ii < 4; ++ii) {
        const int row = bm + wm * 128 + i * 16 + r0 + ii;
        float s = 0.f;
#pragma unroll
        for (int j = 0; j < NR; ++j) {
          const int col = bn + wn * (BN / 4) + j * 16 + c0;
          const u16 h = f2bf(__expf(acc[i][j][ii] * scale));
          ((u16*)Cv)[(size_t)z * sC + (size_t)row * ldC + col] = h;
          s += bf2f(h);                 // sum the SAME bf16 values Pm holds
        }
        s += __shfl_xor(s, 1); s += __shfl_xor(s, 2);
        s += __shfl_xor(s, 4); s += __shfl_xor(s, 8);
        if (c0 == 0)
          part[((size_t)z * 2048 + row) * 32 + (bn >> 8) * 4 + wn] = s;
      }
    }
  } else if constexpr (EPI == 3) {
    // in-block invL: threads 0-255 each reduce one row's 32 partials
    __syncthreads();                    // all LDS traffic of main loop done
    float* sums = reinterpret_cast<float*>(lA);   // 1 KB
    if (t < 256) {
      const float4* pp = reinterpret_cast<const float4*>(
          b0 + ((size_t)z * 2048 + bm + t) * 32);
      float s = 0.f;
#pragma unroll
      for (int q = 0; q < 8; ++q) {
        const float4 v = pp[q];
        s += v.x + v.y + v.z + v.w;
      }
      sums[t] = 1.0f / s;
    }
    __syncthreads();
#pragma unroll
    for (int i = 0; i < 8; ++i) {
#pragma unroll
      for (int ii = 0; ii < 4; ++ii) {
        const int lr = wm * 128 + i * 16 + r0 + ii;
        const float inv = sums[lr];
#pragma unroll
        for (int j = 0; j < NR; ++j) {
          const int col = bn + wn * (BN / 4) + j * 16 + c0;
          // out is never re-read: nontemporal store avoids evicting Pm/vt
          __builtin_nontemporal_store(
              acc[i][j][ii] * inv,
              &((float*)Cv)[(size_t)z * sC + (size_t)(bm + lr) * ldC + col]);
        }
      }
    }
  } else {
#pragma unroll
    for (int i = 0; i < 8; ++i) {
#pragma unroll
      for (int j = 0; j < NR; ++j) {
        const int col = bn + wn * (BN / 4) + j * 16 + c0;
#pragma unroll
        for (int ii = 0; ii < 4; ++ii) {
          const int row = bm + wm * 128 + i * 16 + r0 + ii;
          float v = acc[i][j][ii];
          if constexpr (EPI == 0) {
            const int sel = col >> 10;
            const int cc = col & 1023;
            const float bb = sel == 0 ? b0[cc] : b1[cc];
            ((u16*)Cv)[(size_t)sel * 8388608 + (size_t)row * 1024 + cc] = f2bf(v + bb);
          } else {  // EPI == 1
            ((u16*)Cv)[(size_t)z * sC + (size_t)row * ldC + col] = f2bf(v + b0[row]);
          }
        }
      }
    }
  }
}

// ============================================================================
// Merged projections: blocks 0-255 qk-projection (BN=256, EPI0),
// blocks 256-511 v-projection-transposed (BN=128, EPI1).
// ============================================================================
__global__ __launch_bounds__(512, 2) void proj_k(
    const u16* __restrict__ xb, const u16* __restrict__ wqkv,
    u16* __restrict__ qb, u16* __restrict__ vt,
    const float* __restrict__ bq, const float* __restrict__ bk,
    const float* __restrict__ bv) {
  __shared__ alignas(16) u16 lds[65536];
  if (blockIdx.x < 256) {
    gemm_body<256, 0>(lds, blockIdx.x, 256,
                      xb, wqkv, qb, bq, bk, 2048, E_, 1.f,
                      0, 0, 0, E_, E_, 1024, 8, 32);
  } else {
    gemm_body<128, 1>(lds, blockIdx.x - 256, 256,
                      wqkv + 2 * (size_t)E_ * E_, xb, vt, bv, nullptr,
                      2048, E_, 1.f,
                      0, (long)S_ * E_, (long)1024 * LDP, E_, E_, LDP, 16, 4);
  }
}

// qkt: expS = exp(q k^T / 32) + per-block row partials (no atomics)
__global__ __launch_bounds__(512, 2) void qkt_k(
    const u16* __restrict__ qb, u16* __restrict__ Pm, float* __restrict__ part) {
  __shared__ alignas(16) u16 lds[65536];
  gemm_body<256, 2>(lds, blockIdx.x, 256,
                    qb, qb + 8388608, Pm, part, nullptr, 2048, E_, 0.03125f,
                    (long)S_ * 1024, (long)S_ * 1024, (long)2048 * LDP,
                    1024, 1024, LDP, 8, 8);
}

// pv: out = (expS @ V) / rowsum, BN=128, EPI3 (invL from part in-epilogue)
__global__ __launch_bounds__(512, 2) void pv_k(
    const u16* __restrict__ Pm, const u16* __restrict__ vt,
    float* __restrict__ out, const float* __restrict__ part) {
  __shared__ alignas(16) u16 lds[49152];
  gemm_body<128, 3>(lds, blockIdx.x, 256,
                    Pm, vt, out, part, nullptr, E_, S_, 1.f,
                    (long)2048 * LDP, (long)1024 * LDP, (long)S_ * E_,
                    LDP, LDP, 1024, 8, 8);
}

extern "C" void kernel_launch(void* const* d_in, const int* in_sizes, int n_in,
                              void* d_out, int out_size, void* d_ws, size_t ws_size,
                              hipStream_t stream) {
  const float* x = (const float*)d_in[0];
  const float* Wq = (const float*)d_in[1];
  const float* bq = (const float*)d_in[2];
  const float* Wk = (const float*)d_in[3];
  const float* bk = (const float*)d_in[4];
  const float* Wv = (const float*)d_in[5];
  const float* bv = (const float*)d_in[6];
  float* out = (float*)d_out;

  // workspace (u16 elems): xb 8192x1024, wqkv 3072x1024, q 8192x1024,
  //   k 8192x1024, vt 4x1024xLDP, Pm 4x2048xLDP; then f32 part[8192][32]
  const size_t xE = 8388608, wE = 3145728, qE = 8388608;
  const size_t vtE = (size_t)4 * 1024 * LDP;
  const size_t PmE = (size_t)4 * 2048 * LDP;
  const size_t need = (xE + wE + 2 * qE + vtE + PmE) * 2 + (size_t)MQKV * 32 * 4;
  if (ws_size < need) {
    hipMemsetAsync(d_out, 0, (size_t)out_size * sizeof(float), stream);
    return;
  }
  u16* xb = (u16*)d_ws;
  u16* wqkv = xb + xE;
  u16* qb = wqkv + wE;                  // k at qb + 8388608 (EPI0 hardcodes)
  u16* vt = qb + 2 * qE;
  u16* Pm = vt + vtE;
  float* part = (float*)(Pm + PmE);

  // 1) fp32 -> bf16 for x + all weights (one launch)
  cvt_all<<<2048, 256, 0, stream>>>(x, Wq, Wk, Wv, xb);

  // 2) merged projections: qk (blocks 0-255) + v-transposed (blocks 256-511)
  proj_k<<<512, 512, 0, stream>>>(xb, wqkv, qb, vt, bq, bk, bv);

  // 3) expS = exp(q k^T / 32) + row partials (256 blocks)
  qkt_k<<<256, 512, 0, stream>>>(qb, Pm, part);

  // 4) out = (expS @ V) / rowsum  (256 blocks; invL folded into epilogue)
  pv_k<<<256, 512, 0, stream>>>(Pm, vt, out, part);
}

// Round 21
// 145.816 us; speedup vs baseline: 1.0117x; 1.0117x over previous
//
#include <hip/hip_runtime.h>
#include <stdint.h>

#define B_   4
#define S_   2048
#define E_   1024
#define MQKV (B_ * S_)
#define LDP  2112   // padded row stride (u16) for Pm and vt

typedef __bf16 bf16x8 __attribute__((ext_vector_type(8)));
typedef float f32x4 __attribute__((ext_vector_type(4)));
typedef unsigned short u16;
typedef unsigned int u32;

__device__ __forceinline__ u16 f2bf(float x) {
  union { float f; u32 u; } c; c.f = x;
  u32 r = (c.u + 0x7FFFu + ((c.u >> 16) & 1u)) >> 16;
  return (u16)r;
}
__device__ __forceinline__ float bf2f(u16 h) {
  union { u32 u; float f; } c; c.u = ((u32)h) << 16;
  return c.f;
}

// convert x, Wq, Wk, Wv to bf16 (dst = xb|wqkv contiguous)
__global__ __launch_bounds__(256) void cvt_all(
    const float* __restrict__ x, const float* __restrict__ wq,
    const float* __restrict__ wk, const float* __restrict__ wv,
    u16* __restrict__ dst) {
  const int gid = blockIdx.x * 256 + threadIdx.x;
  const int total = 2097152 + 786432;
  const int stride = gridDim.x * 256;
  for (int i = gid; i < total; i += stride) {
    float4 f;
    if (i < 2097152) {
      f = reinterpret_cast<const float4*>(x)[i];
    } else {
      const int j = i - 2097152;
      const int sel = j >> 18;
      const int r = j & 262143;
      const float* s = sel == 0 ? wq : (sel == 1 ? wk : wv);
      f = reinterpret_cast<const float4*>(s)[r];
    }
    ushort4 o;
    o.x = f2bf(f.x); o.y = f2bf(f.y); o.z = f2bf(f.z); o.w = f2bf(f.w);
    reinterpret_cast<ushort4*>(dst)[i] = o;
  }
}

#define GLOAD_LDS16(g, l)                                                      \
  __builtin_amdgcn_global_load_lds(                                            \
      (const __attribute__((address_space(1))) u32*)(g),                       \
      (__attribute__((address_space(3))) u32*)(l), 16, 0, 0)

// ============================================================================
// R10/R17/R18/R19-verified BK=32 ring GEMM body: BM=256, 8 waves (2Mx4N),
// 4-slot ring, counted vmcnt, 2-way-free XOR swizzle, setprio, XCD swizzle.
// EPI 0: qk-projection: +bias, scatter col<1024 -> q else -> k (ld 1024)
// EPI 1: v-projection-T: +b0[row], bf16, ldC-strided, z-batched
// EPI 2: exp(v*scale), bf16, ldC-strided + per-(row,block,wave) fp32 partial
//        sums via shfl (NO atomics) -> part = (float*)b0, [z][row][32]
// EPI 3: v * invL (invL computed in-epilogue from part = b0), fp32 (final out)
// ============================================================================
template <int BN, int EPI>
__device__ __forceinline__ void gemm_body(
    u16* __restrict__ ldsb, int id, int nwg,
    const u16* __restrict__ A, const u16* __restrict__ Bt, void* __restrict__ Cv,
    const float* __restrict__ b0, const float* __restrict__ b1,
    int N, int K, float scale,
    long sA, long sB, long sC, long ldA, long ldB, long ldC, int gx, int gy) {
  constexpr int BM = 256;
  constexpr int NR = BN / 64;
  constexpr int L  = 2 + BN / 128;
  constexpr int BSLOT = BN * 32;

  u16* lA = ldsb;
  u16* lB = ldsb + 4 * BM * 32;

  const int t = threadIdx.x;
  const int wv = t >> 6;
  const int ln = t & 63;
  const int wm = wv >> 2;
  const int wn = wv & 3;

  id = (id & 7) * (nwg >> 3) + (id >> 3);
  const int pz = gx * gy;
  const int z = id / pz;
  const int r2 = id - z * pz;
  const int by = r2 / gx;
  const int bx = r2 - by * gx;
  const int bm = by * BM;
  const int bn = bx * BN;

  A += (size_t)z * sA;
  Bt += (size_t)z * sB;

  const int srow = t >> 2;
  const int g0 = (t & 3) ^ ((srow >> 1) & 3);
  const u16* gA0 = A + (size_t)(bm + srow) * ldA + g0 * 8;
  const u16* gA1 = gA0 + (size_t)128 * ldA;
  const u16* gB0 = Bt + (size_t)(bn + srow) * ldB + g0 * 8;
  const u16* gB1 = gB0 + (size_t)128 * ldB;

  auto STAGE = [&](int u) {
    const int s = u & 3;
    const int ko = u * 32;
    GLOAD_LDS16(gA0 + ko, lA + s * 8192 + wv * 512);
    GLOAD_LDS16(gA1 + ko, lA + s * 8192 + 4096 + wv * 512);
    GLOAD_LDS16(gB0 + ko, lB + s * BSLOT + wv * 512);
    if constexpr (BN == 256) GLOAD_LDS16(gB1 + ko, lB + s * BSLOT + 4096 + wv * 512);
  };

  const int lrow = ln & 15;
  const int g = ln >> 4;
  const int aR = wm * 128 + lrow;
  const int aOff = aR * 32 + (g ^ ((aR >> 1) & 3)) * 8;
  const int bR = wn * (BN / 4) + lrow;
  const int bOff = bR * 32 + (g ^ ((bR >> 1) & 3)) * 8;

  f32x4 acc[8][NR] = {};
  const int T = K >> 5;

  bf16x8 afA[8], afB[8], bgA[NR], bgB[NR];

#define RD_A(DST, TILE) do { const u16* _p = lA + ((TILE) & 3) * 8192 + aOff;  \
  _Pragma("unroll") for (int _i = 0; _i < 8; ++_i)                             \
    DST[_i] = *reinterpret_cast<const bf16x8*>(_p + _i * 512); } while (0)
#define RD_B(DST, TILE) do { const u16* _p = lB + ((TILE) & 3) * BSLOT + bOff; \
  _Pragma("unroll") for (int _j = 0; _j < NR; ++_j)                            \
    DST[_j] = *reinterpret_cast<const bf16x8*>(_p + _j * 512); } while (0)
#define DO_MFMA(AF, BG) do { __builtin_amdgcn_s_setprio(1);                    \
  _Pragma("unroll") for (int _i = 0; _i < 8; ++_i)                             \
  _Pragma("unroll") for (int _j = 0; _j < NR; ++_j)                            \
    acc[_i][_j] = __builtin_amdgcn_mfma_f32_16x16x32_bf16(AF[_i], BG[_j],      \
                                                          acc[_i][_j], 0, 0, 0);\
  __builtin_amdgcn_s_setprio(0); } while (0)
#define VM_GATE(COND) do {                                                     \
  if (COND) { asm volatile("s_waitcnt vmcnt(%0)" :: "n"(L) : "memory"); }      \
  else { asm volatile("s_waitcnt vmcnt(0)" ::: "memory"); }                    \
  __builtin_amdgcn_s_barrier(); asm volatile("" ::: "memory"); } while (0)

  STAGE(0); STAGE(1); STAGE(2);
  asm volatile("s_waitcnt vmcnt(%0)" :: "n"(L) : "memory");
  __builtin_amdgcn_s_barrier();
  asm volatile("" ::: "memory");

  if constexpr (NR == 2) { RD_A(afA, 0); RD_B(bgA, 0); }
  else                   { RD_B(bgA, 0); }

  for (int tt = 0; tt < T; tt += 2) {
    if (tt + 3 < T) STAGE(tt + 3);
    if constexpr (NR == 2) { RD_A(afB, tt + 1); RD_B(bgB, tt + 1); DO_MFMA(afA, bgA); }
    else                   { RD_A(afA, tt); RD_B(bgB, tt + 1);     DO_MFMA(afA, bgA); }
    VM_GATE(tt + 3 < T);

    if (tt + 4 < T) STAGE(tt + 4);
    if constexpr (NR == 2) {
      if (tt + 2 < T) { RD_A(afA, tt + 2); RD_B(bgA, tt + 2); }
      DO_MFMA(afB, bgB);
    } else {
      RD_A(afA, tt + 1);
      if (tt + 2 < T) RD_B(bgA, tt + 2);
      DO_MFMA(afA, bgB);
    }
    VM_GATE(tt + 4 < T);
  }
#undef RD_A
#undef RD_B
#undef DO_MFMA
#undef VM_GATE

  const int r0 = (ln >> 4) * 4;
  const int c0 = ln & 15;
  if constexpr (EPI == 2) {
    // exp + store + per-row partial (shfl within 16-lane col group, 1 store)
    float* part = const_cast<float*>(b0);
#pragma unroll
    for (int i = 0; i < 8; ++i) {
#pragma unroll
      for (int ii = 0; ii < 4; ++ii) {
        const int row = bm + wm * 128 + i * 16 + r0 + ii;
        float s = 0.f;
#pragma unroll
        for (int j = 0; j < NR; ++j) {
          const int col = bn + wn * (BN / 4) + j * 16 + c0;
          const u16 h = f2bf(__expf(acc[i][j][ii] * scale));
          ((u16*)Cv)[(size_t)z * sC + (size_t)row * ldC + col] = h;
          s += bf2f(h);                 // sum the SAME bf16 values Pm holds
        }
        s += __shfl_xor(s, 1); s += __shfl_xor(s, 2);
        s += __shfl_xor(s, 4); s += __shfl_xor(s, 8);
        if (c0 == 0)
          part[((size_t)z * 2048 + row) * 32 + (bn >> 8) * 4 + wn] = s;
      }
    }
  } else if constexpr (EPI == 3) {
    // in-block invL: threads 0-255 each reduce one row's 32 partials
    __syncthreads();                    // all LDS traffic of main loop done
    float* sums = reinterpret_cast<float*>(lA);   // 1 KB
    if (t < 256) {
      const float4* pp = reinterpret_cast<const float4*>(
          b0 + ((size_t)z * 2048 + bm + t) * 32);
      float s = 0.f;
#pragma unroll
      for (int q = 0; q < 8; ++q) {
        const float4 v = pp[q];
        s += v.x + v.y + v.z + v.w;
      }
      sums[t] = 1.0f / s;
    }
    __syncthreads();
#pragma unroll
    for (int i = 0; i < 8; ++i) {
#pragma unroll
      for (int ii = 0; ii < 4; ++ii) {
        const int lr = wm * 128 + i * 16 + r0 + ii;
        const float inv = sums[lr];
#pragma unroll
        for (int j = 0; j < NR; ++j) {
          const int col = bn + wn * (BN / 4) + j * 16 + c0;
          ((float*)Cv)[(size_t)z * sC + (size_t)(bm + lr) * ldC + col] =
              acc[i][j][ii] * inv;
        }
      }
    }
  } else {
#pragma unroll
    for (int i = 0; i < 8; ++i) {
#pragma unroll
      for (int j = 0; j < NR; ++j) {
        const int col = bn + wn * (BN / 4) + j * 16 + c0;
#pragma unroll
        for (int ii = 0; ii < 4; ++ii) {
          const int row = bm + wm * 128 + i * 16 + r0 + ii;
          float v = acc[i][j][ii];
          if constexpr (EPI == 0) {
            const int sel = col >> 10;
            const int cc = col & 1023;
            const float bb = sel == 0 ? b0[cc] : b1[cc];
            ((u16*)Cv)[(size_t)sel * 8388608 + (size_t)row * 1024 + cc] = f2bf(v + bb);
          } else {  // EPI == 1
            ((u16*)Cv)[(size_t)z * sC + (size_t)row * ldC + col] = f2bf(v + b0[row]);
          }
        }
      }
    }
  }
}

// ============================================================================
// Merged projections: blocks 0-255 qk-projection (BN=256, EPI0),
// blocks 256-511 v-projection-transposed (BN=128, EPI1).
// ============================================================================
__global__ __launch_bounds__(512, 2) void proj_k(
    const u16* __restrict__ xb, const u16* __restrict__ wqkv,
    u16* __restrict__ qb, u16* __restrict__ vt,
    const float* __restrict__ bq, const float* __restrict__ bk,
    const float* __restrict__ bv) {
  __shared__ alignas(16) u16 lds[65536];
  if (blockIdx.x < 256) {
    gemm_body<256, 0>(lds, blockIdx.x, 256,
                      xb, wqkv, qb, bq, bk, 2048, E_, 1.f,
                      0, 0, 0, E_, E_, 1024, 8, 32);
  } else {
    gemm_body<128, 1>(lds, blockIdx.x - 256, 256,
                      wqkv + 2 * (size_t)E_ * E_, xb, vt, bv, nullptr,
                      2048, E_, 1.f,
                      0, (long)S_ * E_, (long)1024 * LDP, E_, E_, LDP, 16, 4);
  }
}

// qkt: expS = exp(q k^T / 32) + per-block row partials (no atomics)
__global__ __launch_bounds__(512, 2) void qkt_k(
    const u16* __restrict__ qb, u16* __restrict__ Pm, float* __restrict__ part) {
  __shared__ alignas(16) u16 lds[65536];
  gemm_body<256, 2>(lds, blockIdx.x, 256,
                    qb, qb + 8388608, Pm, part, nullptr, 2048, E_, 0.03125f,
                    (long)S_ * 1024, (long)S_ * 1024, (long)2048 * LDP,
                    1024, 1024, LDP, 8, 8);
}

// pv: out = (expS @ V) / rowsum, BN=128, EPI3 (invL from part in-epilogue)
__global__ __launch_bounds__(512, 2) void pv_k(
    const u16* __restrict__ Pm, const u16* __restrict__ vt,
    float* __restrict__ out, const float* __restrict__ part) {
  __shared__ alignas(16) u16 lds[49152];
  gemm_body<128, 3>(lds, blockIdx.x, 256,
                    Pm, vt, out, part, nullptr, E_, S_, 1.f,
                    (long)2048 * LDP, (long)1024 * LDP, (long)S_ * E_,
                    LDP, LDP, 1024, 8, 8);
}

extern "C" void kernel_launch(void* const* d_in, const int* in_sizes, int n_in,
                              void* d_out, int out_size, void* d_ws, size_t ws_size,
                              hipStream_t stream) {
  const float* x = (const float*)d_in[0];
  const float* Wq = (const float*)d_in[1];
  const float* bq = (const float*)d_in[2];
  const float* Wk = (const float*)d_in[3];
  const float* bk = (const float*)d_in[4];
  const float* Wv = (const float*)d_in[5];
  const float* bv = (const float*)d_in[6];
  float* out = (float*)d_out;

  // workspace (u16 elems): xb 8192x1024, wqkv 3072x1024, q 8192x1024,
  //   k 8192x1024, vt 4x1024xLDP, Pm 4x2048xLDP; then f32 part[8192][32]
  const size_t xE = 8388608, wE = 3145728, qE = 8388608;
  const size_t vtE = (size_t)4 * 1024 * LDP;
  const size_t PmE = (size_t)4 * 2048 * LDP;
  const size_t need = (xE + wE + 2 * qE + vtE + PmE) * 2 + (size_t)MQKV * 32 * 4;
  if (ws_size < need) {
    hipMemsetAsync(d_out, 0, (size_t)out_size * sizeof(float), stream);
    return;
  }
  u16* xb = (u16*)d_ws;
  u16* wqkv = xb + xE;
  u16* qb = wqkv + wE;                  // k at qb + 8388608 (EPI0 hardcodes)
  u16* vt = qb + 2 * qE;
  u16* Pm = vt + vtE;
  float* part = (float*)(Pm + PmE);

  // 1) fp32 -> bf16 for x + all weights (one launch)
  cvt_all<<<2048, 256, 0, stream>>>(x, Wq, Wk, Wv, xb);

  // 2) merged projections: qk (blocks 0-255) + v-transposed (blocks 256-511)
  proj_k<<<512, 512, 0, stream>>>(xb, wqkv, qb, vt, bq, bk, bv);

  // 3) expS = exp(q k^T / 32) + row partials (256 blocks)
  qkt_k<<<256, 512, 0, stream>>>(qb, Pm, part);

  // 4) out = (expS @ V) / rowsum  (256 blocks; invL folded into epilogue)
  pv_k<<<256, 512, 0, stream>>>(Pm, vt, out, part);
}